// Round 1
// baseline (669.992 us; speedup 1.0000x reference)
//
#include <hip/hip_runtime.h>
#include <stdint.h>

// Problem constants
#define BB 16384
#define II 512
#define HH 1024
#define OO 512
#define KK1 1536   // I + H
#define NN1 4096   // 4*H

typedef short s16x8 __attribute__((ext_vector_type(8)));
typedef float f32x4 __attribute__((ext_vector_type(4)));

__device__ __forceinline__ unsigned short f2bf(float x) {
  union { float f; unsigned u; } v; v.f = x;
  return (unsigned short)((v.u + 0x7fffu + ((v.u >> 16) & 1u)) >> 16);  // RNE
}
__device__ __forceinline__ float bf2f(unsigned short b) {
  union { unsigned u; float f; } v; v.u = ((unsigned)b) << 16;
  return v.f;
}
__device__ __forceinline__ float sigmoid_f(float x) {
  return 1.0f / (1.0f + __expf(-x));   // saturates cleanly, no NaN
}
__device__ __forceinline__ float tanh_f(float x) {
  float ax = fabsf(x);
  float e = __expf(-2.0f * ax);        // -> 0 for large |x|, no inf/NaN
  float t = (1.0f - e) / (1.0f + e);
  return x >= 0.0f ? t : -t;
}

// async global->LDS, 16B per lane, LDS dest = wave-uniform base + lane*16
__device__ __forceinline__ void stage16(const void* g, void* l) {
  __builtin_amdgcn_global_load_lds((const __attribute__((address_space(1))) void*)g,
                                   (__attribute__((address_space(3))) void*)l,
                                   16, 0, 0);
}

// One BK=32 step: 8 ds_read_b128 + 16 MFMA per wave. As/Bs are [128][32] bf16.
__device__ __forceinline__ void mma_step(const unsigned short* As, const unsigned short* Bs,
                                         f32x4 acc[4][4], int lane, int wave) {
  const int wm = wave & 1, wn = wave >> 1;
  const int ln = lane & 15, q = lane >> 4;
  s16x8 af[4], bfr[4];
#pragma unroll
  for (int i = 0; i < 4; ++i)
    af[i] = *(const s16x8*)(As + (wm * 64 + i * 16 + ln) * 32 + q * 8);
#pragma unroll
  for (int i = 0; i < 4; ++i)
    bfr[i] = *(const s16x8*)(Bs + (wn * 64 + i * 16 + ln) * 32 + q * 8);
#pragma unroll
  for (int mi = 0; mi < 4; ++mi)
#pragma unroll
    for (int ni = 0; ni < 4; ++ni)
      acc[mi][ni] = __builtin_amdgcn_mfma_f32_16x16x32_bf16(af[mi], bfr[ni], acc[mi][ni], 0, 0, 0);
}

// ---------------- prep kernels ----------------

// X = [inp | h] -> bf16 [B,1536]; also h_lo = bf16(h - bf16(h)) -> [B,1024]
__global__ __launch_bounds__(256) void prep_X(const float* __restrict__ inp,
                                              const float* __restrict__ h,
                                              unsigned short* __restrict__ Xb,
                                              unsigned short* __restrict__ Hlo) {
  int t = blockIdx.x * 256 + threadIdx.x;
  int base = t * 8;                       // < 25165824
  int b = base / 1536;
  int k = base - b * 1536;
  const float* src = (k < 512) ? (inp + b * 512 + k) : (h + b * 1024 + (k - 512));
  float4 v0 = *(const float4*)src;
  float4 v1 = *(const float4*)(src + 4);
  float f[8] = {v0.x, v0.y, v0.z, v0.w, v1.x, v1.y, v1.z, v1.w};
  unsigned short hi[8];
#pragma unroll
  for (int i = 0; i < 8; ++i) hi[i] = f2bf(f[i]);
  *(s16x8*)(Xb + base) = *(s16x8*)hi;
  if (k >= 512) {
    unsigned short lo[8];
#pragma unroll
    for (int i = 0; i < 8; ++i) lo[i] = f2bf(f[i] - bf2f(hi[i]));
    *(s16x8*)(Hlo + b * 1024 + (k - 512)) = *(s16x8*)lo;
  }
}

// Gate weights -> bf16 [N1=4096][K1=1536], K-contiguous, columns permuted so that
// n = jn*128 + wn*64 + gate*16 + u_lo  <->  unit = jn*32 + wn*16 + u_lo
__global__ __launch_bounds__(256) void prep_Wg(const float* __restrict__ Wx,
                                               const float* __restrict__ Wh,
                                               unsigned short* __restrict__ Wg) {
  int t = blockIdx.x * 256 + threadIdx.x;
  int base = t * 8;                       // < 6291456
  int n = base / 1536;
  int k = base - n * 1536;
  int r = n & 127;
  int gate = (r >> 4) & 3;
  int unit = ((n >> 7) << 5) + (((r >> 6) & 1) << 4) + (r & 15);
  const float* src = (k < 512) ? (Wx + (gate * 1024 + unit) * 512 + k)
                               : (Wh + (gate * 1024 + unit) * 1024 + (k - 512));
  float4 v0 = *(const float4*)src;
  float4 v1 = *(const float4*)(src + 4);
  float f[8] = {v0.x, v0.y, v0.z, v0.w, v1.x, v1.y, v1.z, v1.w};
  unsigned short o[8];
#pragma unroll
  for (int i = 0; i < 8; ++i) o[i] = f2bf(f[i]);
  *(s16x8*)(Wg + base) = *(s16x8*)o;
}

// z-correction weights [1024][2048]: k<1024 -> W_lo(Whz), k>=1024 -> W_hi(Whz)
__global__ __launch_bounds__(256) void prep_Wz2(const float* __restrict__ Whz,
                                                unsigned short* __restrict__ Wz2) {
  int t = blockIdx.x * 256 + threadIdx.x;
  int base = t * 8;                       // < 2097152
  int n = base >> 11;
  int k = base & 2047;
  int klo = (k < 1024) ? k : (k - 1024);
  const float* src = Whz + n * 1024 + klo;
  float4 v0 = *(const float4*)src;
  float4 v1 = *(const float4*)(src + 4);
  float f[8] = {v0.x, v0.y, v0.z, v0.w, v1.x, v1.y, v1.z, v1.w};
  unsigned short o[8];
  if (k < 1024) {
#pragma unroll
    for (int i = 0; i < 8; ++i) { unsigned short h_ = f2bf(f[i]); o[i] = f2bf(f[i] - bf2f(h_)); }
  } else {
#pragma unroll
    for (int i = 0; i < 8; ++i) o[i] = f2bf(f[i]);
  }
  *(s16x8*)(Wz2 + base) = *(s16x8*)o;
}

__global__ __launch_bounds__(256) void prep_Wout(const float* __restrict__ Wout,
                                                 unsigned short* __restrict__ Wo) {
  int t = blockIdx.x * 256 + threadIdx.x;
  int base = t * 8;                       // < 524288
  float4 v0 = *(const float4*)(Wout + base);
  float4 v1 = *(const float4*)(Wout + base + 4);
  float f[8] = {v0.x, v0.y, v0.z, v0.w, v1.x, v1.y, v1.z, v1.w};
  unsigned short o[8];
#pragma unroll
  for (int i = 0; i < 8; ++i) o[i] = f2bf(f[i]);
  *(s16x8*)(Wo + base) = *(s16x8*)o;
}

// ---------------- GEMM kernels ----------------

// Dgz[b,u] = sum_k h_hi*W_lo + h_lo*W_hi   (M=16384, N=1024, K=2048)
__global__ __launch_bounds__(256) void gemm_zcorr(const unsigned short* __restrict__ Xb,
                                                  const unsigned short* __restrict__ Hlo,
                                                  const unsigned short* __restrict__ Wz2,
                                                  unsigned short* __restrict__ Dgz) {
  __shared__ unsigned short As[4096];
  __shared__ unsigned short Bs[4096];
  const int n0 = blockIdx.x * 128;
  const int m0 = blockIdx.y * 128;
  const int tid = threadIdx.x, lane = tid & 63, wave = tid >> 6;
  const int c0 = wave * 64 + lane, c1 = c0 + 256;
  const int r0 = c0 >> 2, kc0 = (c0 & 3) << 3;
  const int r1 = c1 >> 2, kc1 = (c1 & 3) << 3;
  unsigned short* la0 = As + wave * 512;
  unsigned short* la1 = As + 2048 + wave * 512;
  unsigned short* lb0 = Bs + wave * 512;
  unsigned short* lb1 = Bs + 2048 + wave * 512;
  const unsigned short* gb0 = Wz2 + (n0 + r0) * 2048 + kc0;
  const unsigned short* gb1 = Wz2 + (n0 + r1) * 2048 + kc1;
  const int rowA0 = m0 + r0, rowA1 = m0 + r1;
  f32x4 acc[4][4] = {};
  for (int kk = 0; kk < 64; ++kk) {
    const int k0 = kk * 32;
    const unsigned short *ga0, *ga1;
    if (k0 < 1024) {  // h_hi lives inside Xb at column offset 512, ld=1536
      ga0 = Xb + rowA0 * 1536 + 512 + k0 + kc0;
      ga1 = Xb + rowA1 * 1536 + 512 + k0 + kc1;
    } else {          // h_lo, ld=1024
      ga0 = Hlo + rowA0 * 1024 + (k0 - 1024) + kc0;
      ga1 = Hlo + rowA1 * 1024 + (k0 - 1024) + kc1;
    }
    stage16(ga0, la0); stage16(ga1, la1);
    stage16(gb0, lb0); stage16(gb1, lb1);
    gb0 += 32; gb1 += 32;
    __syncthreads();
    mma_step(As, Bs, acc, lane, wave);
    __syncthreads();
  }
  const int wm = wave & 1, wn = wave >> 1;
  const int ln = lane & 15, q = lane >> 4;
#pragma unroll
  for (int mi = 0; mi < 4; ++mi) {
#pragma unroll
    for (int r = 0; r < 4; ++r) {
      const int b = m0 + wm * 64 + mi * 16 + q * 4 + r;
#pragma unroll
      for (int ni = 0; ni < 4; ++ni) {
        const int n = n0 + wn * 64 + ni * 16 + ln;
        Dgz[b * 1024 + n] = f2bf(acc[mi][ni][r]);
      }
    }
  }
}

// Gate GEMM + fused LSTM epilogue. M=16384, N=4096 (permuted), K=1536.
__global__ __launch_bounds__(256) void gemm_gates(const unsigned short* __restrict__ Xb,
                                                   const unsigned short* __restrict__ Wg,
                                                   const float* __restrict__ bx,
                                                   const float* __restrict__ cold,
                                                   const unsigned short* __restrict__ Dgz,
                                                   float* __restrict__ hnew,
                                                   unsigned short* __restrict__ hnewb) {
  __shared__ unsigned short As[4096];
  __shared__ unsigned short Bs[4096];
  const int n0 = blockIdx.x * 128;   // x fastest: co-resident blocks share A rows
  const int m0 = blockIdx.y * 128;
  const int tid = threadIdx.x, lane = tid & 63, wave = tid >> 6;
  const int c0 = wave * 64 + lane, c1 = c0 + 256;
  const int r0 = c0 >> 2, kc0 = (c0 & 3) << 3;
  const int r1 = c1 >> 2, kc1 = (c1 & 3) << 3;
  unsigned short* la0 = As + wave * 512;
  unsigned short* la1 = As + 2048 + wave * 512;
  unsigned short* lb0 = Bs + wave * 512;
  unsigned short* lb1 = Bs + 2048 + wave * 512;
  const unsigned short* ga0 = Xb + (m0 + r0) * 1536 + kc0;
  const unsigned short* ga1 = Xb + (m0 + r1) * 1536 + kc1;
  const unsigned short* gb0 = Wg + (n0 + r0) * 1536 + kc0;
  const unsigned short* gb1 = Wg + (n0 + r1) * 1536 + kc1;
  f32x4 acc[4][4] = {};
  for (int kk = 0; kk < 48; ++kk) {
    stage16(ga0, la0); stage16(ga1, la1);
    stage16(gb0, lb0); stage16(gb1, lb1);
    ga0 += 32; ga1 += 32; gb0 += 32; gb1 += 32;
    __syncthreads();
    mma_step(As, Bs, acc, lane, wave);
    __syncthreads();
  }
  // Epilogue: acc[mi][ni] is gate ni for unit = jn*32 + wn*16 + (lane&15). No cross-lane needed.
  const int wm = wave & 1, wn = wave >> 1;
  const int ln = lane & 15, q = lane >> 4;
  const int unit = (blockIdx.x << 5) + (wn << 4) + ln;
  const float bi = bx[unit];
  const float bo = bx[1024 + unit];
  const float bfg = bx[2048 + unit];
  const float bz = bx[3072 + unit];
#pragma unroll
  for (int mi = 0; mi < 4; ++mi) {
#pragma unroll
    for (int r = 0; r < 4; ++r) {
      const int b = m0 + wm * 64 + mi * 16 + q * 4 + r;
      const int idx = b * 1024 + unit;
      const float gi = acc[mi][0][r] + bi;
      const float go = acc[mi][1][r] + bo;
      const float gf = acc[mi][2][r] + bfg;
      const float gz = acc[mi][3][r] + bz + bf2f(Dgz[idx]);
      const float iv = sigmoid_f(gi);
      const float ov = sigmoid_f(go);
      const float fv = sigmoid_f(gf);
      const float zv = tanh_f(gz);
      const float cn = iv * zv + fv * cold[idx];
      const float hn = ov * tanh_f(cn);
      hnew[idx] = hn;
      hnewb[idx] = f2bf(hn);
    }
  }
}

// out = h_new @ Wout^T + bout. M=16384, N=512, K=1024.
__global__ __launch_bounds__(256) void gemm_out(const unsigned short* __restrict__ Hb,
                                                const unsigned short* __restrict__ Wo,
                                                const float* __restrict__ bout,
                                                float* __restrict__ out) {
  __shared__ unsigned short As[4096];
  __shared__ unsigned short Bs[4096];
  const int n0 = blockIdx.x * 128;
  const int m0 = blockIdx.y * 128;
  const int tid = threadIdx.x, lane = tid & 63, wave = tid >> 6;
  const int c0 = wave * 64 + lane, c1 = c0 + 256;
  const int r0 = c0 >> 2, kc0 = (c0 & 3) << 3;
  const int r1 = c1 >> 2, kc1 = (c1 & 3) << 3;
  unsigned short* la0 = As + wave * 512;
  unsigned short* la1 = As + 2048 + wave * 512;
  unsigned short* lb0 = Bs + wave * 512;
  unsigned short* lb1 = Bs + 2048 + wave * 512;
  const unsigned short* ga0 = Hb + (m0 + r0) * 1024 + kc0;
  const unsigned short* ga1 = Hb + (m0 + r1) * 1024 + kc1;
  const unsigned short* gb0 = Wo + (n0 + r0) * 1024 + kc0;
  const unsigned short* gb1 = Wo + (n0 + r1) * 1024 + kc1;
  f32x4 acc[4][4] = {};
  for (int kk = 0; kk < 32; ++kk) {
    stage16(ga0, la0); stage16(ga1, la1);
    stage16(gb0, lb0); stage16(gb1, lb1);
    ga0 += 32; ga1 += 32; gb0 += 32; gb1 += 32;
    __syncthreads();
    mma_step(As, Bs, acc, lane, wave);
    __syncthreads();
  }
  const int wm = wave & 1, wn = wave >> 1;
  const int ln = lane & 15, q = lane >> 4;
  float bo_[4];
#pragma unroll
  for (int ni = 0; ni < 4; ++ni) bo_[ni] = bout[n0 + wn * 64 + ni * 16 + ln];
#pragma unroll
  for (int mi = 0; mi < 4; ++mi) {
#pragma unroll
    for (int r = 0; r < 4; ++r) {
      const int b = m0 + wm * 64 + mi * 16 + q * 4 + r;
#pragma unroll
      for (int ni = 0; ni < 4; ++ni) {
        const int n = n0 + wn * 64 + ni * 16 + ln;
        out[b * 512 + n] = acc[mi][ni][r] + bo_[ni];
      }
    }
  }
}

extern "C" void kernel_launch(void* const* d_in, const int* in_sizes, int n_in,
                              void* d_out, int out_size, void* d_ws, size_t ws_size,
                              hipStream_t stream) {
  const float* inp  = (const float*)d_in[0];
  const float* h    = (const float*)d_in[1];
  const float* c    = (const float*)d_in[2];
  const float* Wx   = (const float*)d_in[3];
  const float* bx   = (const float*)d_in[4];
  const float* Wh   = (const float*)d_in[5];
  const float* Wout = (const float*)d_in[6];
  const float* bout = (const float*)d_in[7];

  float* out  = (float*)d_out;                       // [B, 512]
  float* hnew = out + (size_t)BB * OO;               // [B, 1024]

  char* ws = (char*)d_ws;
  unsigned short* Xb  = (unsigned short*)(ws);                  //  50,331,648 B
  unsigned short* Wg  = (unsigned short*)(ws + 50331648);       //  12,582,912 B
  unsigned short* Wo  = (unsigned short*)(ws + 62914560);       //   1,048,576 B
  unsigned short* Hb  = (unsigned short*)(ws + 63963136);       //  33,554,432 B
  unsigned short* Hlo = (unsigned short*)(ws + 97517568);       //  33,554,432 B
  unsigned short* Wz2 = (unsigned short*)(ws + 131072000);      //   4,194,304 B
  unsigned short* Dgz = (unsigned short*)(ws + 135266304);      //  33,554,432 B
  // total 168,820,736 B

  prep_X   <<<12288, 256, 0, stream>>>(inp, h, Xb, Hlo);
  prep_Wg  <<<3072,  256, 0, stream>>>(Wx, Wh, Wg);
  prep_Wz2 <<<1024,  256, 0, stream>>>(Wh + 3 * 1024 * 1024, Wz2);
  prep_Wout<<<256,   256, 0, stream>>>(Wout, Wo);
  gemm_zcorr<<<dim3(8, 128),  256, 0, stream>>>(Xb, Hlo, Wz2, Dgz);
  gemm_gates<<<dim3(32, 128), 256, 0, stream>>>(Xb, Wg, bx, c, Dgz, hnew, Hb);
  gemm_out  <<<dim3(4, 128),  256, 0, stream>>>(Hb, Wo, bout, out);
}

// Round 2
// 632.448 us; speedup vs baseline: 1.0594x; 1.0594x over previous
//
#include <hip/hip_runtime.h>
#include <stdint.h>

// Problem constants
#define BB 16384
#define II 512
#define HH 1024
#define OO 512

typedef short s16x8 __attribute__((ext_vector_type(8)));
typedef float f32x4 __attribute__((ext_vector_type(4)));

__device__ __forceinline__ unsigned short f2bf(float x) {
  union { float f; unsigned u; } v; v.f = x;
  return (unsigned short)((v.u + 0x7fffu + ((v.u >> 16) & 1u)) >> 16);  // RNE
}
__device__ __forceinline__ float bf2f(unsigned short b) {
  union { unsigned u; float f; } v; v.u = ((unsigned)b) << 16;
  return v.f;
}
__device__ __forceinline__ float sigmoid_f(float x) {
  return 1.0f / (1.0f + __expf(-x));
}
__device__ __forceinline__ float tanh_f(float x) {
  float ax = fabsf(x);
  float e = __expf(-2.0f * ax);
  float t = (1.0f - e) / (1.0f + e);
  return x >= 0.0f ? t : -t;
}

// async global->LDS, 16B per lane, LDS dest = wave-uniform base + lane*16
__device__ __forceinline__ void stage16(const void* g, void* l) {
  __builtin_amdgcn_global_load_lds((const __attribute__((address_space(1))) void*)g,
                                   (__attribute__((address_space(3))) void*)l,
                                   16, 0, 0);
}

// BK=64 tile: As/Bs are [128][64] bf16 with 16B-chunk swizzle:
// logical chunk j (0..7) of row r lives at byte (r*128 + ((j + r) & 7)*16).
// Reads: sub-step s (k32 block), frag q-chunk -> logical j = s*4+q.
// Bank-quad = (s*4 + q + r) mod 8 -> uniform over all 8 quads per wave read.
__device__ __forceinline__ void mma_step64(const unsigned short* As, const unsigned short* Bs,
                                           f32x4 acc[4][4], int lane, int wave) {
  const int wm = wave & 1, wn = wave >> 1;
  const int ln = lane & 15, q = lane >> 4;
#pragma unroll
  for (int s = 0; s < 2; ++s) {
    s16x8 af[4], bfr[4];
#pragma unroll
    for (int i = 0; i < 4; ++i) {
      const int r = wm * 64 + i * 16 + ln;
      af[i] = *(const s16x8*)(As + r * 64 + ((((s << 2) + q) + r) & 7) * 8);
    }
#pragma unroll
    for (int i = 0; i < 4; ++i) {
      const int r = wn * 64 + i * 16 + ln;
      bfr[i] = *(const s16x8*)(Bs + r * 64 + ((((s << 2) + q) + r) & 7) * 8);
    }
#pragma unroll
    for (int mi = 0; mi < 4; ++mi)
#pragma unroll
      for (int ni = 0; ni < 4; ++ni)
        acc[mi][ni] = __builtin_amdgcn_mfma_f32_16x16x32_bf16(af[mi], bfr[ni], acc[mi][ni], 0, 0, 0);
  }
}

// ---------------- prep kernels ----------------

__global__ __launch_bounds__(256) void prep_X(const float* __restrict__ inp,
                                              const float* __restrict__ h,
                                              unsigned short* __restrict__ Xb,
                                              unsigned short* __restrict__ Hlo) {
  int t = blockIdx.x * 256 + threadIdx.x;
  int base = t * 8;
  int b = base / 1536;
  int k = base - b * 1536;
  const float* src = (k < 512) ? (inp + b * 512 + k) : (h + b * 1024 + (k - 512));
  float4 v0 = *(const float4*)src;
  float4 v1 = *(const float4*)(src + 4);
  float f[8] = {v0.x, v0.y, v0.z, v0.w, v1.x, v1.y, v1.z, v1.w};
  unsigned short hi[8];
#pragma unroll
  for (int i = 0; i < 8; ++i) hi[i] = f2bf(f[i]);
  *(s16x8*)(Xb + base) = *(s16x8*)hi;
  if (k >= 512) {
    unsigned short lo[8];
#pragma unroll
    for (int i = 0; i < 8; ++i) lo[i] = f2bf(f[i] - bf2f(hi[i]));
    *(s16x8*)(Hlo + b * 1024 + (k - 512)) = *(s16x8*)lo;
  }
}

// Gate weights -> bf16 [4096][1536], K-contiguous, columns permuted so that
// n = jn*128 + wn*64 + gate*16 + u_lo  <->  unit = jn*32 + wn*16 + u_lo
__global__ __launch_bounds__(256) void prep_Wg(const float* __restrict__ Wx,
                                               const float* __restrict__ Wh,
                                               unsigned short* __restrict__ Wg) {
  int t = blockIdx.x * 256 + threadIdx.x;
  int base = t * 8;
  int n = base / 1536;
  int k = base - n * 1536;
  int r = n & 127;
  int gate = (r >> 4) & 3;
  int unit = ((n >> 7) << 5) + (((r >> 6) & 1) << 4) + (r & 15);
  const float* src = (k < 512) ? (Wx + (gate * 1024 + unit) * 512 + k)
                               : (Wh + (gate * 1024 + unit) * 1024 + (k - 512));
  float4 v0 = *(const float4*)src;
  float4 v1 = *(const float4*)(src + 4);
  float f[8] = {v0.x, v0.y, v0.z, v0.w, v1.x, v1.y, v1.z, v1.w};
  unsigned short o[8];
#pragma unroll
  for (int i = 0; i < 8; ++i) o[i] = f2bf(f[i]);
  *(s16x8*)(Wg + base) = *(s16x8*)o;
}

// z-correction weights [1024][2048]: k<1024 -> W_lo(Whz), k>=1024 -> W_hi(Whz)
__global__ __launch_bounds__(256) void prep_Wz2(const float* __restrict__ Whz,
                                                unsigned short* __restrict__ Wz2) {
  int t = blockIdx.x * 256 + threadIdx.x;
  int base = t * 8;
  int n = base >> 11;
  int k = base & 2047;
  int klo = (k < 1024) ? k : (k - 1024);
  const float* src = Whz + n * 1024 + klo;
  float4 v0 = *(const float4*)src;
  float4 v1 = *(const float4*)(src + 4);
  float f[8] = {v0.x, v0.y, v0.z, v0.w, v1.x, v1.y, v1.z, v1.w};
  unsigned short o[8];
  if (k < 1024) {
#pragma unroll
    for (int i = 0; i < 8; ++i) { unsigned short h_ = f2bf(f[i]); o[i] = f2bf(f[i] - bf2f(h_)); }
  } else {
#pragma unroll
    for (int i = 0; i < 8; ++i) o[i] = f2bf(f[i]);
  }
  *(s16x8*)(Wz2 + base) = *(s16x8*)o;
}

__global__ __launch_bounds__(256) void prep_Wout(const float* __restrict__ Wout,
                                                 unsigned short* __restrict__ Wo) {
  int t = blockIdx.x * 256 + threadIdx.x;
  int base = t * 8;
  float4 v0 = *(const float4*)(Wout + base);
  float4 v1 = *(const float4*)(Wout + base + 4);
  float f[8] = {v0.x, v0.y, v0.z, v0.w, v1.x, v1.y, v1.z, v1.w};
  unsigned short o[8];
#pragma unroll
  for (int i = 0; i < 8; ++i) o[i] = f2bf(f[i]);
  *(s16x8*)(Wo + base) = *(s16x8*)o;
}

// ---------------- GEMM kernels ----------------
// Staging map (BK=64): thread stages 4 A + 4 B chunks. Chunk position
// p = u*256 + tid -> LDS byte p*16; row r = p>>3, stored slot c = p&7,
// logical chunk j = (c - r) & 7, global elem offset = r*ld + j*8.

// Dgz[b,u] = sum_k h_hi*W_lo + h_lo*W_hi   (M=16384, N=1024, K=2048)
__global__ __launch_bounds__(256) void gemm_zcorr(const unsigned short* __restrict__ Xb,
                                                  const unsigned short* __restrict__ Hlo,
                                                  const unsigned short* __restrict__ Wz2,
                                                  unsigned short* __restrict__ Dgz) {
  __shared__ unsigned short As[8192];
  __shared__ unsigned short Bs[8192];
  const int n0 = blockIdx.x * 128;
  const int m0 = blockIdx.y * 128;
  const int tid = threadIdx.x, lane = tid & 63, wave = tid >> 6;
  const unsigned short *gaX[4], *gaH[4], *gb[4];
  unsigned short *la[4], *lb[4];
#pragma unroll
  for (int u = 0; u < 4; ++u) {
    int p = u * 256 + tid;
    int r = p >> 3;
    int j = ((p & 7) - r) & 7;
    gaX[u] = Xb + (size_t)(m0 + r) * 1536 + 512 + j * 8;
    gaH[u] = Hlo + (size_t)(m0 + r) * 1024 + j * 8;
    gb[u]  = Wz2 + (size_t)(n0 + r) * 2048 + j * 8;
    la[u] = As + (u * 256 + (tid & ~63)) * 8;
    lb[u] = Bs + (u * 256 + (tid & ~63)) * 8;
  }
  f32x4 acc[4][4] = {};
  for (int kk = 0; kk < 16; ++kk) {   // phase 1: h_hi (in Xb) x W_lo
#pragma unroll
    for (int u = 0; u < 4; ++u) { stage16(gaX[u], la[u]); stage16(gb[u], lb[u]); }
#pragma unroll
    for (int u = 0; u < 4; ++u) { gaX[u] += 64; gb[u] += 64; }
    __syncthreads();
    mma_step64(As, Bs, acc, lane, wave);
    __syncthreads();
  }
  for (int kk = 0; kk < 16; ++kk) {   // phase 2: h_lo x W_hi
#pragma unroll
    for (int u = 0; u < 4; ++u) { stage16(gaH[u], la[u]); stage16(gb[u], lb[u]); }
#pragma unroll
    for (int u = 0; u < 4; ++u) { gaH[u] += 64; gb[u] += 64; }
    __syncthreads();
    mma_step64(As, Bs, acc, lane, wave);
    __syncthreads();
  }
  const int wm = wave & 1, wn = wave >> 1;
  const int ln = lane & 15, q = lane >> 4;
#pragma unroll
  for (int mi = 0; mi < 4; ++mi) {
#pragma unroll
    for (int r = 0; r < 4; ++r) {
      const int b = m0 + wm * 64 + mi * 16 + q * 4 + r;
#pragma unroll
      for (int ni = 0; ni < 4; ++ni) {
        const int n = n0 + wn * 64 + ni * 16 + ln;
        Dgz[b * 1024 + n] = f2bf(acc[mi][ni][r]);
      }
    }
  }
}

// Gate GEMM + fused LSTM epilogue. M=16384, N=4096 (permuted), K=1536.
__global__ __launch_bounds__(256) void gemm_gates(const unsigned short* __restrict__ Xb,
                                                   const unsigned short* __restrict__ Wg,
                                                   const float* __restrict__ bx,
                                                   const float* __restrict__ cold,
                                                   const unsigned short* __restrict__ Dgz,
                                                   float* __restrict__ hnew,
                                                   unsigned short* __restrict__ hnewb) {
  __shared__ unsigned short As[8192];
  __shared__ unsigned short Bs[8192];
  const int n0 = blockIdx.x * 128;   // x fastest: co-resident blocks share A rows
  const int m0 = blockIdx.y * 128;
  const int tid = threadIdx.x, lane = tid & 63, wave = tid >> 6;
  const unsigned short *ga[4], *gb[4];
  unsigned short *la[4], *lb[4];
#pragma unroll
  for (int u = 0; u < 4; ++u) {
    int p = u * 256 + tid;
    int r = p >> 3;
    int j = ((p & 7) - r) & 7;
    ga[u] = Xb + (size_t)(m0 + r) * 1536 + j * 8;
    gb[u] = Wg + (size_t)(n0 + r) * 1536 + j * 8;
    la[u] = As + (u * 256 + (tid & ~63)) * 8;
    lb[u] = Bs + (u * 256 + (tid & ~63)) * 8;
  }
  f32x4 acc[4][4] = {};
  for (int kk = 0; kk < 24; ++kk) {
#pragma unroll
    for (int u = 0; u < 4; ++u) { stage16(ga[u], la[u]); stage16(gb[u], lb[u]); }
#pragma unroll
    for (int u = 0; u < 4; ++u) { ga[u] += 64; gb[u] += 64; }
    __syncthreads();
    mma_step64(As, Bs, acc, lane, wave);
    __syncthreads();
  }
  // Epilogue: acc[mi][ni] is gate ni for unit = blockIdx.x*32 + wn*16 + ln.
  const int wm = wave & 1, wn = wave >> 1;
  const int ln = lane & 15, q = lane >> 4;
  const int unit = (blockIdx.x << 5) + (wn << 4) + ln;
  const float bi = bx[unit];
  const float bo = bx[1024 + unit];
  const float bfg = bx[2048 + unit];
  const float bz = bx[3072 + unit];
#pragma unroll
  for (int mi = 0; mi < 4; ++mi) {
#pragma unroll
    for (int r = 0; r < 4; ++r) {
      const int b = m0 + wm * 64 + mi * 16 + q * 4 + r;
      const int idx = b * 1024 + unit;
      const float gi = acc[mi][0][r] + bi;
      const float go = acc[mi][1][r] + bo;
      const float gf = acc[mi][2][r] + bfg;
      const float gz = acc[mi][3][r] + bz + bf2f(Dgz[idx]);
      const float iv = sigmoid_f(gi);
      const float ov = sigmoid_f(go);
      const float fv = sigmoid_f(gf);
      const float zv = tanh_f(gz);
      const float cn = iv * zv + fv * cold[idx];
      const float hn = ov * tanh_f(cn);
      hnew[idx] = hn;
      hnewb[idx] = f2bf(hn);
    }
  }
}

// out = h_new @ Wout^T + bout. M=16384, N=512, K=1024.
__global__ __launch_bounds__(256) void gemm_out(const unsigned short* __restrict__ Hb,
                                                const unsigned short* __restrict__ Wo,
                                                const float* __restrict__ bout,
                                                float* __restrict__ out) {
  __shared__ unsigned short As[8192];
  __shared__ unsigned short Bs[8192];
  const int n0 = blockIdx.x * 128;
  const int m0 = blockIdx.y * 128;
  const int tid = threadIdx.x, lane = tid & 63, wave = tid >> 6;
  const unsigned short *ga[4], *gb[4];
  unsigned short *la[4], *lb[4];
#pragma unroll
  for (int u = 0; u < 4; ++u) {
    int p = u * 256 + tid;
    int r = p >> 3;
    int j = ((p & 7) - r) & 7;
    ga[u] = Hb + (size_t)(m0 + r) * 1024 + j * 8;
    gb[u] = Wo + (size_t)(n0 + r) * 1024 + j * 8;
    la[u] = As + (u * 256 + (tid & ~63)) * 8;
    lb[u] = Bs + (u * 256 + (tid & ~63)) * 8;
  }
  f32x4 acc[4][4] = {};
  for (int kk = 0; kk < 16; ++kk) {
#pragma unroll
    for (int u = 0; u < 4; ++u) { stage16(ga[u], la[u]); stage16(gb[u], lb[u]); }
#pragma unroll
    for (int u = 0; u < 4; ++u) { ga[u] += 64; gb[u] += 64; }
    __syncthreads();
    mma_step64(As, Bs, acc, lane, wave);
    __syncthreads();
  }
  const int wm = wave & 1, wn = wave >> 1;
  const int ln = lane & 15, q = lane >> 4;
  float bo_[4];
#pragma unroll
  for (int ni = 0; ni < 4; ++ni) bo_[ni] = bout[n0 + wn * 64 + ni * 16 + ln];
#pragma unroll
  for (int mi = 0; mi < 4; ++mi) {
#pragma unroll
    for (int r = 0; r < 4; ++r) {
      const int b = m0 + wm * 64 + mi * 16 + q * 4 + r;
#pragma unroll
      for (int ni = 0; ni < 4; ++ni) {
        const int n = n0 + wn * 64 + ni * 16 + ln;
        out[b * 512 + n] = acc[mi][ni][r] + bo_[ni];
      }
    }
  }
}

extern "C" void kernel_launch(void* const* d_in, const int* in_sizes, int n_in,
                              void* d_out, int out_size, void* d_ws, size_t ws_size,
                              hipStream_t stream) {
  const float* inp  = (const float*)d_in[0];
  const float* h    = (const float*)d_in[1];
  const float* c    = (const float*)d_in[2];
  const float* Wx   = (const float*)d_in[3];
  const float* bx   = (const float*)d_in[4];
  const float* Wh   = (const float*)d_in[5];
  const float* Wout = (const float*)d_in[6];
  const float* bout = (const float*)d_in[7];

  float* out  = (float*)d_out;                       // [B, 512]
  float* hnew = out + (size_t)BB * OO;               // [B, 1024]

  char* ws = (char*)d_ws;
  unsigned short* Xb  = (unsigned short*)(ws);                  //  50,331,648 B
  unsigned short* Wg  = (unsigned short*)(ws + 50331648);       //  12,582,912 B
  unsigned short* Wo  = (unsigned short*)(ws + 62914560);       //   1,048,576 B
  unsigned short* Hb  = (unsigned short*)(ws + 63963136);       //  33,554,432 B
  unsigned short* Hlo = (unsigned short*)(ws + 97517568);       //  33,554,432 B
  unsigned short* Wz2 = (unsigned short*)(ws + 131072000);      //   4,194,304 B
  unsigned short* Dgz = (unsigned short*)(ws + 135266304);      //  33,554,432 B

  prep_X   <<<12288, 256, 0, stream>>>(inp, h, Xb, Hlo);
  prep_Wg  <<<3072,  256, 0, stream>>>(Wx, Wh, Wg);
  prep_Wz2 <<<1024,  256, 0, stream>>>(Wh + 3 * 1024 * 1024, Wz2);
  prep_Wout<<<256,   256, 0, stream>>>(Wout, Wo);
  gemm_zcorr<<<dim3(8, 128),  256, 0, stream>>>(Xb, Hlo, Wz2, Dgz);
  gemm_gates<<<dim3(32, 128), 256, 0, stream>>>(Xb, Wg, bx, c, Dgz, hnew, Hb);
  gemm_out  <<<dim3(4, 128),  256, 0, stream>>>(Hb, Wo, bout, out);
}